// Round 1
// baseline (4664.864 us; speedup 1.0000x reference)
//
#include <hip/hip_runtime.h>
#include <hip/hip_bf16.h>

// LVAttNet: 2x GRU(128) over 9 obs steps + 8 autoregressive steps, B=32768.
// Persistent wave design: each wave owns 16 batch rows for the whole network.
// Gates computed transposed (D = W * x^T) so h_new's C/D register layout IS
// the B-fragment layout for the next step's recurrent matmul (zero shuffle).

typedef __attribute__((ext_vector_type(8))) short short8;
typedef __attribute__((ext_vector_type(4))) float float4v;

#define NB 32768

__device__ __forceinline__ ushort bfc(float x) {
  // fp32 -> bf16 bits, round-to-nearest-even
  uint u = __builtin_bit_cast(uint, x);
  uint r = (u + 0x7fffu + ((u >> 16) & 1u)) >> 16;
  return (ushort)r;
}

__device__ __forceinline__ float4v mfma16(short8 a, short8 b, float4v c) {
  return __builtin_amdgcn_mfma_f32_16x16x32_bf16(a, b, c, 0, 0, 0);
}

__device__ __forceinline__ float sigm(float x) {
  return __fdividef(1.0f, 1.0f + __expf(-x));
}
__device__ __forceinline__ float tanh_(float x) {
  return 1.0f - __fdividef(2.0f, 1.0f + __expf(2.0f * x));
}

// k position mapping inside a 32-wide K tile for (group g, pos p).
// Chosen as "split half" (two K=16 subtiles); A and B use the SAME map, so any
// HW permutation over (g,p) cancels in the dot product.
__device__ __host__ __forceinline__ int kmap(int g, int p) {
  return (p < 4) ? (4 * g + p) : (16 + 4 * g + (p - 4));
}

// ---------------- prep: pack 4x (384,128) fp32 weights into bf16 A-fragments
// tile = mt*4+kt (mt: 16 gate rows, kt: 32 k). frag addr = ((mat*96+tile)*64+lane)*16B
__global__ void pack_w(const float* __restrict__ w0, const float* __restrict__ w1,
                       const float* __restrict__ w2, const float* __restrict__ w3,
                       short8* __restrict__ outp) {
  int t = blockIdx.x * 256 + threadIdx.x;
  if (t >= 4 * 96 * 64) return;
  int lane = t & 63;
  int tile = (t >> 6) % 96;
  int mat = t / 6144;
  const float* W = (mat == 0) ? w0 : (mat == 1) ? w1 : (mat == 2) ? w2 : w3;
  int mt = tile >> 2, kt = tile & 3;
  int g = lane >> 4, q = lane & 15;
  int row = mt * 16 + q;
  union { ushort u[8]; short8 v; } pw;
#pragma unroll
  for (int p = 0; p < 8; ++p) {
    int k = kt * 32 + kmap(g, p);
    pw.u[p] = bfc(W[row * 128 + k]);
  }
  outp[t] = pw.v;
}

// ---------------- main persistent kernel ----------------
__global__ __launch_bounds__(256, 2) void lvatt_main(
    const float* __restrict__ obs, const float* __restrict__ hidden,
    const float* __restrict__ W_le, const float* __restrict__ b_le,
    const float* __restrict__ W_ve, const float* __restrict__ b_ve,
    const float* __restrict__ bih_l, const float* __restrict__ bhh_l,
    const float* __restrict__ bih_v, const float* __restrict__ bhh_v,
    const float* __restrict__ W_lo, const float* __restrict__ b_lo,
    const float* __restrict__ W_vo, const float* __restrict__ b_vo,
    const float* __restrict__ W_at, const float* __restrict__ b_at,
    const short8* __restrict__ wpack, float* __restrict__ out) {
  __shared__ alignas(16) float s_we[2][128][4];   // {w0,w1,b,0} per embed dim
  __shared__ alignas(16) float s_brc[2][128];     // bih_r + bhh_r
  __shared__ alignas(16) float s_bzc[2][128];     // bih_z + bhh_z
  __shared__ alignas(16) float s_bin[2][128];     // bih_n
  __shared__ alignas(16) float s_bhn[2][128];     // bhh_n
  __shared__ alignas(16) float s_wo[2][2][128];   // output heads
  __shared__ float s_sm[16];

  int tid = threadIdx.x;
  if (tid < 128) {
    s_we[0][tid][0] = W_le[tid * 2]; s_we[0][tid][1] = W_le[tid * 2 + 1];
    s_we[0][tid][2] = b_le[tid];     s_we[0][tid][3] = 0.f;
    s_we[1][tid][0] = W_ve[tid * 2]; s_we[1][tid][1] = W_ve[tid * 2 + 1];
    s_we[1][tid][2] = b_ve[tid];     s_we[1][tid][3] = 0.f;
    s_brc[0][tid] = bih_l[tid] + bhh_l[tid];
    s_bzc[0][tid] = bih_l[128 + tid] + bhh_l[128 + tid];
    s_bin[0][tid] = bih_l[256 + tid];
    s_bhn[0][tid] = bhh_l[256 + tid];
    s_brc[1][tid] = bih_v[tid] + bhh_v[tid];
    s_bzc[1][tid] = bih_v[128 + tid] + bhh_v[128 + tid];
    s_bin[1][tid] = bih_v[256 + tid];
    s_bhn[1][tid] = bhh_v[256 + tid];
    s_wo[0][0][tid] = W_lo[tid]; s_wo[0][1][tid] = W_lo[128 + tid];
    s_wo[1][0][tid] = W_vo[tid]; s_wo[1][1][tid] = W_vo[128 + tid];
  }
  if (tid < 2) {
    s_sm[tid] = b_lo[tid];
    s_sm[2 + tid] = b_vo[tid];
    s_sm[12 + tid] = b_at[tid];
  }
  if (tid < 8) s_sm[4 + tid] = W_at[tid];
  __syncthreads();

  int lane = tid & 63;
  int g = lane >> 4, q = lane & 15;
  int wv = tid >> 6;
  int row = (blockIdx.x * 4 + wv) * 16 + q;

  // h state: h32[gru][mt][r] = h[batch=q][hcol=16*mt+4*g+r]  (fp32 master)
  float h32[2][8][4];
  short8 hfr[2][4];  // bf16 B-fragments of h (kt = 0..3)
  short8 efr[2][4];  // bf16 B-fragments of embedding

#pragma unroll
  for (int mt = 0; mt < 8; ++mt) {
    float4v hv = *(const float4v*)(hidden + row * 128 + mt * 16 + 4 * g);
#pragma unroll
    for (int r = 0; r < 4; ++r) { h32[0][mt][r] = hv[r]; h32[1][mt][r] = hv[r]; }
  }
#pragma unroll
  for (int gg = 0; gg < 2; ++gg)
#pragma unroll
    for (int mt = 0; mt < 8; ++mt)
#pragma unroll
      for (int r = 0; r < 4; ++r)
        hfr[gg][mt >> 1][(mt & 1) * 4 + r] = (short)bfc(h32[gg][mt][r]);

  float a0 = 0.f, a1 = 0.f, a2 = 0.f, a3 = 0.f;  // last_in / autoregressive input

#pragma unroll 1
  for (int t = 0; t < 17; ++t) {
    float xi00, xi01, xi10, xi11;
    if (t < 9) {
      float4v o = *(const float4v*)(obs + (row * 9 + t) * 4);
      xi00 = o[0]; xi01 = o[1]; xi10 = o[2]; xi11 = o[3];
      if (t == 8) { a0 = o[0]; a1 = o[1]; a2 = o[2]; a3 = o[3]; }
    } else {
      xi00 = a0; xi01 = a1; xi10 = a2; xi11 = a3;
    }

#pragma unroll
    for (int gg = 0; gg < 2; ++gg) {
      float x0 = gg ? xi10 : xi00;
      float x1 = gg ? xi11 : xi01;
      // embedding: emb[e] = relu(x0*W[e][0] + x1*W[e][1] + b[e]), e = 16mt+4g+r
#pragma unroll
      for (int mt = 0; mt < 8; ++mt) {
#pragma unroll
        for (int r = 0; r < 4; ++r) {
          int e = mt * 16 + 4 * g + r;
          float4v we = *(const float4v*)(&s_we[gg][e][0]);
          float v = fmaxf(fmaf(we[0], x0, fmaf(we[1], x1, we[2])), 0.f);
          efr[gg][mt >> 1][(mt & 1) * 4 + r] = (short)bfc(v);
        }
      }
      const short8* wih = wpack + (size_t)(gg * 2 + 0) * 6144;
      const short8* whh = wpack + (size_t)(gg * 2 + 1) * 6144;
#pragma unroll
      for (int ct = 0; ct < 8; ++ct) {
        int bofs = ct * 16 + 4 * g;
        float4v air = *(const float4v*)(&s_brc[gg][bofs]);
        float4v aiz = *(const float4v*)(&s_bzc[gg][bofs]);
        float4v ain = *(const float4v*)(&s_bin[gg][bofs]);
        float4v ahn = *(const float4v*)(&s_bhn[gg][bofs]);
        float4v ahr = {0.f, 0.f, 0.f, 0.f};
        float4v ahz = {0.f, 0.f, 0.f, 0.f};
#pragma unroll
        for (int kt = 0; kt < 4; ++kt) {
          short8 bE = efr[gg][kt];
          short8 bH = hfr[gg][kt];
          short8 wir = wih[((ct) * 4 + kt) * 64 + lane];
          short8 wiz = wih[((8 + ct) * 4 + kt) * 64 + lane];
          short8 win = wih[((16 + ct) * 4 + kt) * 64 + lane];
          short8 whr = whh[((ct) * 4 + kt) * 64 + lane];
          short8 whz = whh[((8 + ct) * 4 + kt) * 64 + lane];
          short8 whn = whh[((16 + ct) * 4 + kt) * 64 + lane];
          air = mfma16(wir, bE, air);
          aiz = mfma16(wiz, bE, aiz);
          ain = mfma16(win, bE, ain);
          ahr = mfma16(whr, bH, ahr);
          ahz = mfma16(whz, bH, ahz);
          ahn = mfma16(whn, bH, ahn);
        }
#pragma unroll
        for (int r = 0; r < 4; ++r) {
          float rr = sigm(air[r] + ahr[r]);
          float zz = sigm(aiz[r] + ahz[r]);
          float nn = tanh_(fmaf(rr, ahn[r], ain[r]));
          h32[gg][ct][r] = fmaf(zz, h32[gg][ct][r] - nn, nn);  // n + z*(h-n)
        }
      }
      // refresh bf16 h fragments for next step (old ones fully consumed above)
#pragma unroll
      for (int mt = 0; mt < 8; ++mt)
#pragma unroll
        for (int r = 0; r < 4; ++r)
          hfr[gg][mt >> 1][(mt & 1) * 4 + r] = (short)bfc(h32[gg][mt][r]);
    }

    if (t >= 8) {
      // pred = [h_loc @ W_lo^T + b_lo, h_vel @ W_vo^T + b_vo] (fp32 dot)
      float p0 = 0.f, p1 = 0.f, p2 = 0.f, p3 = 0.f;
#pragma unroll
      for (int mt = 0; mt < 8; ++mt) {
        int o = mt * 16 + 4 * g;
        float4v wa = *(const float4v*)(&s_wo[0][0][o]);
        float4v wb = *(const float4v*)(&s_wo[0][1][o]);
        float4v wc = *(const float4v*)(&s_wo[1][0][o]);
        float4v wd = *(const float4v*)(&s_wo[1][1][o]);
#pragma unroll
        for (int r = 0; r < 4; ++r) {
          p0 = fmaf(h32[0][mt][r], wa[r], p0);
          p1 = fmaf(h32[0][mt][r], wb[r], p1);
          p2 = fmaf(h32[1][mt][r], wc[r], p2);
          p3 = fmaf(h32[1][mt][r], wd[r], p3);
        }
      }
      // reduce partials across the 4 lane-groups (same batch row q)
      p0 += __shfl_xor(p0, 16); p0 += __shfl_xor(p0, 32);
      p1 += __shfl_xor(p1, 16); p1 += __shfl_xor(p1, 32);
      p2 += __shfl_xor(p2, 16); p2 += __shfl_xor(p2, 32);
      p3 += __shfl_xor(p3, 16); p3 += __shfl_xor(p3, 32);
      p0 += s_sm[0]; p1 += s_sm[1]; p2 += s_sm[2]; p3 += s_sm[3];
      float t0 = fmaf(p0, s_sm[4], fmaf(p1, s_sm[5], fmaf(p2, s_sm[6], fmaf(p3, s_sm[7], s_sm[12]))));
      float t1 = fmaf(p0, s_sm[8], fmaf(p1, s_sm[9], fmaf(p2, s_sm[10], fmaf(p3, s_sm[11], s_sm[13]))));
      float mx = fmaxf(t0, t1);
      float e0 = __expf(t0 - mx), e1 = __expf(t1 - mx);
      float al = __fdividef(e0, e0 + e1);
      float av = 1.0f - al;
      float x0 = a0, y0 = a1;
      float nx = al * p0 + av * (x0 + p2);
      float ny = al * p1 + av * (y0 + p3);
      a0 = nx; a1 = ny; a2 = nx - x0; a3 = ny - y0;
      if (t > 8 && lane < 16) {
        float2 o2; o2.x = nx; o2.y = ny;
        *(float2*)(out + row * 16 + (t - 9) * 2) = o2;  // preds[(t-9)] = (nx,ny)
      }
    }
  }
}

extern "C" void kernel_launch(void* const* d_in, const int* in_sizes, int n_in,
                              void* d_out, int out_size, void* d_ws, size_t ws_size,
                              hipStream_t stream) {
  const float* obs = (const float*)d_in[0];
  const float* hid = (const float*)d_in[1];
  const float* W_le = (const float*)d_in[2];
  const float* b_le = (const float*)d_in[3];
  const float* W_ve = (const float*)d_in[4];
  const float* b_ve = (const float*)d_in[5];
  const float* Wih_l = (const float*)d_in[6];
  const float* Whh_l = (const float*)d_in[7];
  const float* bih_l = (const float*)d_in[8];
  const float* bhh_l = (const float*)d_in[9];
  const float* Wih_v = (const float*)d_in[10];
  const float* Whh_v = (const float*)d_in[11];
  const float* bih_v = (const float*)d_in[12];
  const float* bhh_v = (const float*)d_in[13];
  const float* W_lo = (const float*)d_in[14];
  const float* b_lo = (const float*)d_in[15];
  const float* W_vo = (const float*)d_in[16];
  const float* b_vo = (const float*)d_in[17];
  const float* W_at = (const float*)d_in[18];
  const float* b_at = (const float*)d_in[19];

  short8* wp = (short8*)d_ws;  // needs 4*96*64*16 = 393216 B of scratch

  hipLaunchKernelGGL(pack_w, dim3(96), dim3(256), 0, stream,
                     Wih_l, Whh_l, Wih_v, Whh_v, wp);
  hipLaunchKernelGGL(lvatt_main, dim3(NB / 64), dim3(256), 0, stream,
                     obs, hid, W_le, b_le, W_ve, b_ve,
                     bih_l, bhh_l, bih_v, bhh_v,
                     W_lo, b_lo, W_vo, b_vo, W_at, b_at,
                     (const short8*)wp, (float*)d_out);
}

// Round 2
// 981.795 us; speedup vs baseline: 4.7514x; 4.7514x over previous
//
#include <hip/hip_runtime.h>
#include <hip/hip_bf16.h>

// LVAttNet: 2x GRU(128) over 9 obs + 8 autoregressive steps, B=32768.
// R2: weights staged through double-buffered LDS (global_load_lds, 16B),
// shared by all 8 waves of a 512-thread block. Each wave owns 16 batch rows;
// gates computed transposed (D = W * x^T) so h_new's C/D layout IS the next
// step's B-fragment layout (zero-shuffle recurrence, h never leaves regs).

typedef __attribute__((ext_vector_type(8))) short short8;
typedef __attribute__((ext_vector_type(4))) float float4v;

#define NB 32768

__device__ __forceinline__ ushort bfc(float x) {
  uint u = __builtin_bit_cast(uint, x);
  uint r = (u + 0x7fffu + ((u >> 16) & 1u)) >> 16;
  return (ushort)r;
}

__device__ __forceinline__ float4v mfma16(short8 a, short8 b, float4v c) {
  return __builtin_amdgcn_mfma_f32_16x16x32_bf16(a, b, c, 0, 0, 0);
}

__device__ __forceinline__ float sigm(float x) {
  return __fdividef(1.0f, 1.0f + __expf(-x));
}
__device__ __forceinline__ float tanh_(float x) {
  return 1.0f - __fdividef(2.0f, 1.0f + __expf(2.0f * x));
}

// k position mapping inside a 32-wide K tile for (group g, pos p).
// A and B use the SAME map, so any HW permutation over (g,p) cancels.
__device__ __host__ __forceinline__ int kmap(int g, int p) {
  return (p < 4) ? (4 * g + p) : (16 + 4 * g + (p - 4));
}

// ---------------- prep: pack 4x (384,128) fp32 weights into bf16 A-fragments
// tile = mt*4+kt. frag addr = ((mat*96+tile)*64+lane) in short8 units.
__global__ void pack_w(const float* __restrict__ w0, const float* __restrict__ w1,
                       const float* __restrict__ w2, const float* __restrict__ w3,
                       short8* __restrict__ outp) {
  int t = blockIdx.x * 256 + threadIdx.x;
  if (t >= 4 * 96 * 64) return;
  int lane = t & 63;
  int tile = (t >> 6) % 96;
  int mat = t / 6144;
  const float* W = (mat == 0) ? w0 : (mat == 1) ? w1 : (mat == 2) ? w2 : w3;
  int mt = tile >> 2, kt = tile & 3;
  int g = lane >> 4, q = lane & 15;
  int row = mt * 16 + q;
  union { ushort u[8]; short8 v; } pw;
#pragma unroll
  for (int p = 0; p < 8; ++p) {
    int k = kt * 32 + kmap(g, p);
    pw.u[p] = bfc(W[row * 128 + k]);
  }
  outp[t] = pw.v;
}

// async global->LDS, 16B per lane; l must be wave-uniform (HW adds lane*16)
__device__ __forceinline__ void gl_lds16(const short8* g, short8* l) {
  __builtin_amdgcn_global_load_lds(
      (const __attribute__((address_space(1))) unsigned int*)g,
      (__attribute__((address_space(3))) unsigned int*)l, 16, 0, 0);
}

// stage one (gg,ct) chunk: 24 fragments x 1KB. wave wv stages 3 of them.
__device__ __forceinline__ void stage_chunk(const short8* __restrict__ wpack,
                                            short8* buf, int gg, int ct,
                                            int wv, int lane) {
#pragma unroll
  for (int j = 0; j < 3; ++j) {
    int f = wv * 3 + j;          // 0..23
    int m = f >> 2, kt = f & 3;  // m: {ihr,ihz,ihn,hhr,hhz,hhn}
    int mm = (m >= 3) ? (m - 3) : m;
    int mat = gg * 2 + ((m >= 3) ? 1 : 0);
    int G = mm * 8 + ct;
    const short8* g = wpack + ((size_t)(mat * 96 + G * 4 + kt) * 64 + lane);
    gl_lds16(g, buf + f * 64);
  }
}

// ---------------- main persistent kernel ----------------
__global__ __launch_bounds__(512, 2) void lvatt_main(
    const float* __restrict__ obs, const float* __restrict__ hidden,
    const float* __restrict__ W_le, const float* __restrict__ b_le,
    const float* __restrict__ W_ve, const float* __restrict__ b_ve,
    const float* __restrict__ bih_l, const float* __restrict__ bhh_l,
    const float* __restrict__ bih_v, const float* __restrict__ bhh_v,
    const float* __restrict__ W_lo, const float* __restrict__ b_lo,
    const float* __restrict__ W_vo, const float* __restrict__ b_vo,
    const float* __restrict__ W_at, const float* __restrict__ b_at,
    const short8* __restrict__ wpack, float* __restrict__ out) {
  __shared__ alignas(16) short8 s_wbuf[2][24 * 64];  // 2 x 24 KB weight chunks
  __shared__ alignas(16) float s_we[2][128][4];      // {w0,w1,b,0} per embed dim
  __shared__ alignas(16) float s_brc[2][128];
  __shared__ alignas(16) float s_bzc[2][128];
  __shared__ alignas(16) float s_bin[2][128];
  __shared__ alignas(16) float s_bhn[2][128];
  __shared__ alignas(16) float s_wo[2][2][128];
  __shared__ float s_sm[16];

  int tid = threadIdx.x;
  if (tid < 128) {
    s_we[0][tid][0] = W_le[tid * 2]; s_we[0][tid][1] = W_le[tid * 2 + 1];
    s_we[0][tid][2] = b_le[tid];     s_we[0][tid][3] = 0.f;
    s_we[1][tid][0] = W_ve[tid * 2]; s_we[1][tid][1] = W_ve[tid * 2 + 1];
    s_we[1][tid][2] = b_ve[tid];     s_we[1][tid][3] = 0.f;
    s_brc[0][tid] = bih_l[tid] + bhh_l[tid];
    s_bzc[0][tid] = bih_l[128 + tid] + bhh_l[128 + tid];
    s_bin[0][tid] = bih_l[256 + tid];
    s_bhn[0][tid] = bhh_l[256 + tid];
    s_brc[1][tid] = bih_v[tid] + bhh_v[tid];
    s_bzc[1][tid] = bih_v[128 + tid] + bhh_v[128 + tid];
    s_bin[1][tid] = bih_v[256 + tid];
    s_bhn[1][tid] = bhh_v[256 + tid];
    s_wo[0][0][tid] = W_lo[tid]; s_wo[0][1][tid] = W_lo[128 + tid];
    s_wo[1][0][tid] = W_vo[tid]; s_wo[1][1][tid] = W_vo[128 + tid];
  }
  if (tid < 2) {
    s_sm[tid] = b_lo[tid];
    s_sm[2 + tid] = b_vo[tid];
    s_sm[12 + tid] = b_at[tid];
  }
  if (tid < 8) s_sm[4 + tid] = W_at[tid];

  int lane = tid & 63;
  int g = lane >> 4, q = lane & 15;
  int wv = tid >> 6;                           // 0..7
  int row = (blockIdx.x * 8 + wv) * 16 + q;

  float h32[2][8][4];
  short8 hfr[2][4];
  short8 efr[2][4];

#pragma unroll
  for (int mt = 0; mt < 8; ++mt) {
    float4v hv = *(const float4v*)(hidden + row * 128 + mt * 16 + 4 * g);
#pragma unroll
    for (int r = 0; r < 4; ++r) { h32[0][mt][r] = hv[r]; h32[1][mt][r] = hv[r]; }
  }
#pragma unroll
  for (int gg = 0; gg < 2; ++gg)
#pragma unroll
    for (int mt = 0; mt < 8; ++mt)
#pragma unroll
      for (int r = 0; r < 4; ++r)
        hfr[gg][mt >> 1][(mt & 1) * 4 + r] = (short)bfc(h32[gg][mt][r]);

  float a0 = 0.f, a1 = 0.f, a2 = 0.f, a3 = 0.f;

  __syncthreads();                // consts visible
  stage_chunk(wpack, s_wbuf[0], 0, 0, wv, lane);   // prefetch chunk 0
  __syncthreads();                // drains vmcnt(0): buf0 ready

  int cur = 0;
#pragma unroll 1
  for (int t = 0; t < 17; ++t) {
    float xi00, xi01, xi10, xi11;
    if (t < 9) {
      float4v o = *(const float4v*)(obs + (row * 9 + t) * 4);
      xi00 = o[0]; xi01 = o[1]; xi10 = o[2]; xi11 = o[3];
      if (t == 8) { a0 = o[0]; a1 = o[1]; a2 = o[2]; a3 = o[3]; }
    } else {
      xi00 = a0; xi01 = a1; xi10 = a2; xi11 = a3;
    }

    // embeddings for both GRUs (consumed as B-fragments all step)
#pragma unroll
    for (int gg = 0; gg < 2; ++gg) {
      float x0 = gg ? xi10 : xi00;
      float x1 = gg ? xi11 : xi01;
#pragma unroll
      for (int mt = 0; mt < 8; ++mt) {
#pragma unroll
        for (int r = 0; r < 4; ++r) {
          int e = mt * 16 + 4 * g + r;
          float4v we = *(const float4v*)(&s_we[gg][e][0]);
          float v = fmaxf(fmaf(we[0], x0, fmaf(we[1], x1, we[2])), 0.f);
          efr[gg][mt >> 1][(mt & 1) * 4 + r] = (short)bfc(v);
        }
      }
    }

    // 16 chunks: gg 0..1 x ct 0..7, fully unrolled (static reg indices)
#pragma unroll
    for (int gg = 0; gg < 2; ++gg) {
#pragma unroll
      for (int ct = 0; ct < 8; ++ct) {
        int c = gg * 8 + ct;
        // issue async stage of next chunk into the other buffer
        if (t * 16 + c < 271) {
          int n = (c + 1) & 15;
          stage_chunk(wpack, s_wbuf[cur ^ 1], n >> 3, n & 7, wv, lane);
        }
        const short8* wb = s_wbuf[cur];
        int bofs = ct * 16 + 4 * g;
        float4v air = *(const float4v*)(&s_brc[gg][bofs]);
        float4v aiz = *(const float4v*)(&s_bzc[gg][bofs]);
        float4v ain = *(const float4v*)(&s_bin[gg][bofs]);
        float4v ahn = *(const float4v*)(&s_bhn[gg][bofs]);
        float4v ahr = {0.f, 0.f, 0.f, 0.f};
        float4v ahz = {0.f, 0.f, 0.f, 0.f};
#pragma unroll
        for (int kt = 0; kt < 4; ++kt) {
          short8 bE = efr[gg][kt];
          short8 bH = hfr[gg][kt];
          short8 wir = wb[(0 * 4 + kt) * 64 + lane];
          short8 wiz = wb[(1 * 4 + kt) * 64 + lane];
          short8 win = wb[(2 * 4 + kt) * 64 + lane];
          short8 whr = wb[(3 * 4 + kt) * 64 + lane];
          short8 whz = wb[(4 * 4 + kt) * 64 + lane];
          short8 whn = wb[(5 * 4 + kt) * 64 + lane];
          air = mfma16(wir, bE, air);
          aiz = mfma16(wiz, bE, aiz);
          ain = mfma16(win, bE, ain);
          ahr = mfma16(whr, bH, ahr);
          ahz = mfma16(whz, bH, ahz);
          ahn = mfma16(whn, bH, ahn);
        }
#pragma unroll
        for (int r = 0; r < 4; ++r) {
          float rr = sigm(air[r] + ahr[r]);
          float zz = sigm(aiz[r] + ahz[r]);
          float nn = tanh_(fmaf(rr, ahn[r], ain[r]));
          h32[gg][ct][r] = fmaf(zz, h32[gg][ct][r] - nn, nn);
        }
        if (ct == 7) {  // all of this GRU's chunks done: refresh h fragments
#pragma unroll
          for (int mt = 0; mt < 8; ++mt)
#pragma unroll
            for (int r = 0; r < 4; ++r)
              hfr[gg][mt >> 1][(mt & 1) * 4 + r] = (short)bfc(h32[gg][mt][r]);
        }
        __syncthreads();  // drains DMA (next buf ready) + all waves done with cur
        cur ^= 1;
      }
    }

    if (t >= 8) {
      float p0 = 0.f, p1 = 0.f, p2 = 0.f, p3 = 0.f;
#pragma unroll
      for (int mt = 0; mt < 8; ++mt) {
        int o = mt * 16 + 4 * g;
        float4v wa = *(const float4v*)(&s_wo[0][0][o]);
        float4v wb2 = *(const float4v*)(&s_wo[0][1][o]);
        float4v wc = *(const float4v*)(&s_wo[1][0][o]);
        float4v wd = *(const float4v*)(&s_wo[1][1][o]);
#pragma unroll
        for (int r = 0; r < 4; ++r) {
          p0 = fmaf(h32[0][mt][r], wa[r], p0);
          p1 = fmaf(h32[0][mt][r], wb2[r], p1);
          p2 = fmaf(h32[1][mt][r], wc[r], p2);
          p3 = fmaf(h32[1][mt][r], wd[r], p3);
        }
      }
      p0 += __shfl_xor(p0, 16); p0 += __shfl_xor(p0, 32);
      p1 += __shfl_xor(p1, 16); p1 += __shfl_xor(p1, 32);
      p2 += __shfl_xor(p2, 16); p2 += __shfl_xor(p2, 32);
      p3 += __shfl_xor(p3, 16); p3 += __shfl_xor(p3, 32);
      p0 += s_sm[0]; p1 += s_sm[1]; p2 += s_sm[2]; p3 += s_sm[3];
      float t0 = fmaf(p0, s_sm[4], fmaf(p1, s_sm[5], fmaf(p2, s_sm[6], fmaf(p3, s_sm[7], s_sm[12]))));
      float t1 = fmaf(p0, s_sm[8], fmaf(p1, s_sm[9], fmaf(p2, s_sm[10], fmaf(p3, s_sm[11], s_sm[13]))));
      float mx = fmaxf(t0, t1);
      float e0 = __expf(t0 - mx), e1 = __expf(t1 - mx);
      float al = __fdividef(e0, e0 + e1);
      float av = 1.0f - al;
      float x0 = a0, y0 = a1;
      float nx = al * p0 + av * (x0 + p2);
      float ny = al * p1 + av * (y0 + p3);
      a0 = nx; a1 = ny; a2 = nx - x0; a3 = ny - y0;
      if (t > 8 && lane < 16) {
        float2 o2; o2.x = nx; o2.y = ny;
        *(float2*)(out + row * 16 + (t - 9) * 2) = o2;
      }
    }
  }
}

extern "C" void kernel_launch(void* const* d_in, const int* in_sizes, int n_in,
                              void* d_out, int out_size, void* d_ws, size_t ws_size,
                              hipStream_t stream) {
  const float* obs = (const float*)d_in[0];
  const float* hid = (const float*)d_in[1];
  const float* W_le = (const float*)d_in[2];
  const float* b_le = (const float*)d_in[3];
  const float* W_ve = (const float*)d_in[4];
  const float* b_ve = (const float*)d_in[5];
  const float* Wih_l = (const float*)d_in[6];
  const float* Whh_l = (const float*)d_in[7];
  const float* bih_l = (const float*)d_in[8];
  const float* bhh_l = (const float*)d_in[9];
  const float* Wih_v = (const float*)d_in[10];
  const float* Whh_v = (const float*)d_in[11];
  const float* bih_v = (const float*)d_in[12];
  const float* bhh_v = (const float*)d_in[13];
  const float* W_lo = (const float*)d_in[14];
  const float* b_lo = (const float*)d_in[15];
  const float* W_vo = (const float*)d_in[16];
  const float* b_vo = (const float*)d_in[17];
  const float* W_at = (const float*)d_in[18];
  const float* b_at = (const float*)d_in[19];

  short8* wp = (short8*)d_ws;  // 4*96*64*16 = 393216 B of scratch

  hipLaunchKernelGGL(pack_w, dim3(96), dim3(256), 0, stream,
                     Wih_l, Whh_l, Wih_v, Whh_v, wp);
  hipLaunchKernelGGL(lvatt_main, dim3(NB / 128), dim3(512), 0, stream,
                     obs, hid, W_le, b_le, W_ve, b_ve,
                     bih_l, bhh_l, bih_v, bhh_v,
                     W_lo, b_lo, W_vo, b_vo, W_at, b_at,
                     (const short8*)wp, (float*)d_out);
}

// Round 3
// 423.267 us; speedup vs baseline: 11.0211x; 2.3196x over previous
//
#include <hip/hip_runtime.h>
#include <hip/hip_bf16.h>

// LVAttNet R3 "B-prime": weights register-resident, activations through LDS.
// 8 waves/block; wave (gru,j) owns h-cols 32j..32j+31 of one GRU for all 128
// batch rows of the block. Zero steady-state global traffic; ~9 barriers/step.

typedef __attribute__((ext_vector_type(8))) short short8;
typedef __attribute__((ext_vector_type(4))) float float4v;

#define NB 32768

// dynamic LDS layout (bytes)
#define OFF_EMBF 0         // [2][8][4] frags x 1KB = 64KB
#define OFF_HF   65536     // [2][8][4] frags x 1KB = 64KB
#define OFF_WE   131072    // [2][128][4] f32 (w0,w1,b,pad) = 4KB
#define OFF_BIAS 135168    // [2][4][128] f32 (r,z,in,hn)   = 4KB
#define OFF_WOP  139264    // [2][128][2] f32 head weights  = 2KB
#define OFF_PART 141312    // [2][4][8][16][2] f32 partials = 8KB
#define OFF_PRED 149504    // [128][4] f32 = 2KB
#define OFF_A    151552    // [128][4] f32 = 2KB
#define OFF_AT   153600    // [16] f32
#define DYN_LDS  153664

__device__ __forceinline__ ushort bfc(float x) {
  uint u = __builtin_bit_cast(uint, x);
  uint r = (u + 0x7fffu + ((u >> 16) & 1u)) >> 16;
  return (ushort)r;
}
__device__ __forceinline__ float bf2f(ushort b) {
  return __builtin_bit_cast(float, (uint)b << 16);
}
__device__ __forceinline__ float4v mfma16(short8 a, short8 b, float4v c) {
  return __builtin_amdgcn_mfma_f32_16x16x32_bf16(a, b, c, 0, 0, 0);
}
__device__ __forceinline__ float sigm(float x) {
  return __fdividef(1.0f, 1.0f + __expf(-x));
}
__device__ __forceinline__ float tanh_(float x) {
  return 1.0f - __fdividef(2.0f, 1.0f + __expf(2.0f * x));
}

// k position inside a 32-wide K tile for (group g, pos p). A-pack and all
// B-fragment construction use the SAME map -> HW permutation cancels.
__device__ __host__ __forceinline__ int kmap(int g, int p) {
  return (p < 4) ? (4 * g + p) : (16 + 4 * g + (p - 4));
}

// pack 4x (384,128) fp32 weights into bf16 A-fragments.
// frag addr = ((mat*96 + mt*4 + kt)*64 + lane) in short8 units.
__global__ void pack_w(const float* __restrict__ w0, const float* __restrict__ w1,
                       const float* __restrict__ w2, const float* __restrict__ w3,
                       short8* __restrict__ outp) {
  int t = blockIdx.x * 256 + threadIdx.x;
  if (t >= 4 * 96 * 64) return;
  int lane = t & 63;
  int tile = (t >> 6) % 96;
  int mat = t / 6144;
  const float* W = (mat == 0) ? w0 : (mat == 1) ? w1 : (mat == 2) ? w2 : w3;
  int mt = tile >> 2, kt = tile & 3;
  int g = lane >> 4, q = lane & 15;
  int row = mt * 16 + q;
  union { ushort u[8]; short8 v; } pw;
#pragma unroll
  for (int p = 0; p < 8; ++p) {
    int k = kt * 32 + kmap(g, p);
    pw.u[p] = bfc(W[row * 128 + k]);
  }
  outp[t] = pw.v;
}

__global__ __launch_bounds__(512, 2) void lvatt_main(
    const float* __restrict__ obs, const float* __restrict__ hidden,
    const float* __restrict__ W_le, const float* __restrict__ b_le,
    const float* __restrict__ W_ve, const float* __restrict__ b_ve,
    const float* __restrict__ bih_l, const float* __restrict__ bhh_l,
    const float* __restrict__ bih_v, const float* __restrict__ bhh_v,
    const float* __restrict__ W_lo, const float* __restrict__ b_lo,
    const float* __restrict__ W_vo, const float* __restrict__ b_vo,
    const float* __restrict__ W_at, const float* __restrict__ b_at,
    const short8* __restrict__ wpack, float* __restrict__ out) {
  extern __shared__ char smem[];
  short8* embF = (short8*)(smem + OFF_EMBF);
  short8* hF = (short8*)(smem + OFF_HF);
  float* s_we = (float*)(smem + OFF_WE);
  float* s_bias = (float*)(smem + OFF_BIAS);
  float* s_wop = (float*)(smem + OFF_WOP);
  float* s_part = (float*)(smem + OFF_PART);
  float* s_pred = (float*)(smem + OFF_PRED);
  float* s_a = (float*)(smem + OFF_A);
  float* s_at = (float*)(smem + OFF_AT);

  const int tid = threadIdx.x;
  const int lane = tid & 63;
  const int g = (lane >> 4) & 3;
  const int q = lane & 15;
  const int wv = tid >> 6;
  const int gru = wv & 1;
  const int j = wv >> 1;
  const int base = blockIdx.x * 128;

  if (tid < 128) {
    int col = tid;
    s_we[(0 * 128 + col) * 4 + 0] = W_le[col * 2];
    s_we[(0 * 128 + col) * 4 + 1] = W_le[col * 2 + 1];
    s_we[(0 * 128 + col) * 4 + 2] = b_le[col];
    s_we[(0 * 128 + col) * 4 + 3] = 0.f;
    s_we[(1 * 128 + col) * 4 + 0] = W_ve[col * 2];
    s_we[(1 * 128 + col) * 4 + 1] = W_ve[col * 2 + 1];
    s_we[(1 * 128 + col) * 4 + 2] = b_ve[col];
    s_we[(1 * 128 + col) * 4 + 3] = 0.f;
    s_bias[(0 * 4 + 0) * 128 + col] = bih_l[col] + bhh_l[col];
    s_bias[(0 * 4 + 1) * 128 + col] = bih_l[128 + col] + bhh_l[128 + col];
    s_bias[(0 * 4 + 2) * 128 + col] = bih_l[256 + col];
    s_bias[(0 * 4 + 3) * 128 + col] = bhh_l[256 + col];
    s_bias[(1 * 4 + 0) * 128 + col] = bih_v[col] + bhh_v[col];
    s_bias[(1 * 4 + 1) * 128 + col] = bih_v[128 + col] + bhh_v[128 + col];
    s_bias[(1 * 4 + 2) * 128 + col] = bih_v[256 + col];
    s_bias[(1 * 4 + 3) * 128 + col] = bhh_v[256 + col];
    s_wop[(0 * 128 + col) * 2 + 0] = W_lo[col];
    s_wop[(0 * 128 + col) * 2 + 1] = W_lo[128 + col];
    s_wop[(1 * 128 + col) * 2 + 0] = W_vo[col];
    s_wop[(1 * 128 + col) * 2 + 1] = W_vo[128 + col];
  }
  if (tid < 4) s_at[tid] = (tid < 2) ? b_lo[tid] : b_vo[tid - 2];
  else if (tid < 12) s_at[tid] = W_at[tid - 4];
  else if (tid < 14) s_at[tid] = b_at[tid - 12];

  // register-resident A fragments: 48 frags = 192 VGPRs
  short8 aih[3][2][4], ahh[3][2][4];
#pragma unroll
  for (int G = 0; G < 3; ++G)
#pragma unroll
    for (int c2 = 0; c2 < 2; ++c2)
#pragma unroll
      for (int kt = 0; kt < 4; ++kt) {
        int mt = G * 8 + 2 * j + c2;
        aih[G][c2][kt] = wpack[(size_t)(((gru * 2 + 0) * 96 + mt * 4 + kt) * 64 + lane)];
        ahh[G][c2][kt] = wpack[(size_t)(((gru * 2 + 1) * 96 + mt * 4 + kt) * 64 + lane)];
      }

  // initial h fragments from `hidden`
#pragma unroll 1
  for (int nt = 0; nt < 8; ++nt) {
    const float* hp = hidden + (size_t)(base + nt * 16 + q) * 128 + 32 * j + 4 * g;
    float4v h0a = *(const float4v*)(hp);
    float4v h0b = *(const float4v*)(hp + 16);
    union { ushort u[8]; short8 v; } h8;
#pragma unroll
    for (int r = 0; r < 4; ++r) { h8.u[r] = bfc(h0a[r]); h8.u[4 + r] = bfc(h0b[r]); }
    hF[((gru * 8 + nt) * 4 + j) * 64 + lane] = h8.v;
  }
  __syncthreads();

#pragma unroll 1
  for (int t = 0; t < 17; ++t) {
    // ---- embedding phase: wave (gru,j) produces emb frags kt=j for all nt
    float4v wcol[8];
#pragma unroll
    for (int c2 = 0; c2 < 2; ++c2)
#pragma unroll
      for (int r = 0; r < 4; ++r) {
        int col = 32 * j + 16 * c2 + 4 * g + r;
        wcol[c2 * 4 + r] = *(const float4v*)&s_we[(gru * 128 + col) * 4];
      }
#pragma unroll 1
    for (int nt = 0; nt < 8; ++nt) {
      float x0, x1;
      if (t < 9) {
        const float* op = obs + (size_t)(base + nt * 16 + q) * 36 + t * 4 + 2 * gru;
        x0 = op[0]; x1 = op[1];
      } else {
        const float* ap = s_a + (nt * 16 + q) * 4 + 2 * gru;
        x0 = ap[0]; x1 = ap[1];
      }
      union { ushort u[8]; short8 v; } e8;
#pragma unroll
      for (int p = 0; p < 8; ++p)
        e8.u[p] = bfc(fmaxf(fmaf(wcol[p][0], x0, fmaf(wcol[p][1], x1, wcol[p][2])), 0.f));
      embF[((gru * 8 + nt) * 4 + j) * 64 + lane] = e8.v;
    }
    __syncthreads();

    // ---- GRU phase: per batch tile nt
#pragma unroll 1
    for (int nt = 0; nt < 8; ++nt) {
      const int fb = (gru * 8 + nt) * 4;
      float4v racc[2], zacc[2], inacc[2], hnacc[2];
#pragma unroll
      for (int c2 = 0; c2 < 2; ++c2) {
        int colA = 32 * j + 16 * c2 + 4 * g;
        racc[c2] = *(const float4v*)&s_bias[(gru * 4 + 0) * 128 + colA];
        zacc[c2] = *(const float4v*)&s_bias[(gru * 4 + 1) * 128 + colA];
        inacc[c2] = *(const float4v*)&s_bias[(gru * 4 + 2) * 128 + colA];
        hnacc[c2] = *(const float4v*)&s_bias[(gru * 4 + 3) * 128 + colA];
      }
      short8 hj = hF[(fb + j) * 64 + lane];  // own cols: h_old source
#pragma unroll
      for (int kt = 0; kt < 4; ++kt) {
        short8 bE = embF[(fb + kt) * 64 + lane];
        short8 bH = hF[(fb + kt) * 64 + lane];
#pragma unroll
        for (int c2 = 0; c2 < 2; ++c2) {
          racc[c2] = mfma16(aih[0][c2][kt], bE, racc[c2]);
          racc[c2] = mfma16(ahh[0][c2][kt], bH, racc[c2]);
          zacc[c2] = mfma16(aih[1][c2][kt], bE, zacc[c2]);
          zacc[c2] = mfma16(ahh[1][c2][kt], bH, zacc[c2]);
          inacc[c2] = mfma16(aih[2][c2][kt], bE, inacc[c2]);
          hnacc[c2] = mfma16(ahh[2][c2][kt], bH, hnacc[c2]);
        }
      }
      union { ushort u[8]; short8 v; } hjv; hjv.v = hj;
      union { ushort u[8]; short8 v; } nh;
      float hnew[8];
#pragma unroll
      for (int c2 = 0; c2 < 2; ++c2)
#pragma unroll
        for (int r = 0; r < 4; ++r) {
          int p = c2 * 4 + r;
          float hold = bf2f(hjv.u[p]);
          float rr = sigm(racc[c2][r]);
          float zz = sigm(zacc[c2][r]);
          float nn = tanh_(fmaf(rr, hnacc[c2][r], inacc[c2][r]));
          float hv = fmaf(zz, hold - nn, nn);
          hnew[p] = hv;
          nh.u[p] = bfc(hv);
        }
      if (t >= 8) {  // head partials for this nt (own 32 cols)
        float p0 = 0.f, p1 = 0.f;
#pragma unroll
        for (int c2 = 0; c2 < 2; ++c2) {
          int colA = 32 * j + 16 * c2 + 4 * g;
          float4v w01 = *(const float4v*)&s_wop[(gru * 128 + colA) * 2];
          float4v w23 = *(const float4v*)&s_wop[(gru * 128 + colA + 2) * 2];
          p0 += hnew[c2 * 4 + 0] * w01[0] + hnew[c2 * 4 + 1] * w01[2] +
                hnew[c2 * 4 + 2] * w23[0] + hnew[c2 * 4 + 3] * w23[2];
          p1 += hnew[c2 * 4 + 0] * w01[1] + hnew[c2 * 4 + 1] * w01[3] +
                hnew[c2 * 4 + 2] * w23[1] + hnew[c2 * 4 + 3] * w23[3];
        }
        p0 += __shfl_xor(p0, 16); p0 += __shfl_xor(p0, 32);
        p1 += __shfl_xor(p1, 16); p1 += __shfl_xor(p1, 32);
        if (lane < 16) {
          float2 pw; pw.x = p0; pw.y = p1;
          *(float2*)&s_part[(((gru * 4 + j) * 8 + nt) * 16 + q) * 2] = pw;
        }
      }
      __syncthreads();  // all reads of frag[nt] done -> safe to overwrite
      hF[(fb + j) * 64 + lane] = nh.v;
    }

    // ---- head + attention + tweak (t >= 8)
    if (t >= 8) {
      {
        int b = tid >> 2, v = tid & 3;
        int gr = v >> 1, vv = v & 1;
        float s = s_at[v];
#pragma unroll
        for (int jj = 0; jj < 4; ++jj)
          s += s_part[(((gr * 4 + jj) * 8 + (b >> 4)) * 16 + (b & 15)) * 2 + vv];
        s_pred[b * 4 + v] = s;
      }
      __syncthreads();
      if (tid < 128) {
        int b = tid;
        float4v p = *(const float4v*)&s_pred[b * 4];
        float x0, y0;
        if (t == 8) {
          const float* op = obs + (size_t)(base + b) * 36 + 32;
          x0 = op[0]; y0 = op[1];
        } else {
          x0 = s_a[b * 4]; y0 = s_a[b * 4 + 1];
        }
        float t0 = fmaf(p[0], s_at[4], fmaf(p[1], s_at[5], fmaf(p[2], s_at[6], fmaf(p[3], s_at[7], s_at[12]))));
        float t1 = fmaf(p[0], s_at[8], fmaf(p[1], s_at[9], fmaf(p[2], s_at[10], fmaf(p[3], s_at[11], s_at[13]))));
        float al = sigm(t0 - t1);
        float av = 1.0f - al;
        float nx = al * p[0] + av * (x0 + p[2]);
        float ny = al * p[1] + av * (y0 + p[3]);
        float4v an; an[0] = nx; an[1] = ny; an[2] = nx - x0; an[3] = ny - y0;
        *(float4v*)&s_a[b * 4] = an;
        if (t > 8) {
          float2 o2; o2.x = nx; o2.y = ny;
          *(float2*)(out + (size_t)(base + b) * 16 + (t - 9) * 2) = o2;
        }
      }
      __syncthreads();
    }
  }
}

extern "C" void kernel_launch(void* const* d_in, const int* in_sizes, int n_in,
                              void* d_out, int out_size, void* d_ws, size_t ws_size,
                              hipStream_t stream) {
  const float* obs = (const float*)d_in[0];
  const float* hid = (const float*)d_in[1];
  const float* W_le = (const float*)d_in[2];
  const float* b_le = (const float*)d_in[3];
  const float* W_ve = (const float*)d_in[4];
  const float* b_ve = (const float*)d_in[5];
  const float* Wih_l = (const float*)d_in[6];
  const float* Whh_l = (const float*)d_in[7];
  const float* bih_l = (const float*)d_in[8];
  const float* bhh_l = (const float*)d_in[9];
  const float* Wih_v = (const float*)d_in[10];
  const float* Whh_v = (const float*)d_in[11];
  const float* bih_v = (const float*)d_in[12];
  const float* bhh_v = (const float*)d_in[13];
  const float* W_lo = (const float*)d_in[14];
  const float* b_lo = (const float*)d_in[15];
  const float* W_vo = (const float*)d_in[16];
  const float* b_vo = (const float*)d_in[17];
  const float* W_at = (const float*)d_in[18];
  const float* b_at = (const float*)d_in[19];

  short8* wp = (short8*)d_ws;  // 4*96*64*16 = 393216 B of scratch

  hipFuncSetAttribute(reinterpret_cast<const void*>(lvatt_main),
                      hipFuncAttributeMaxDynamicSharedMemorySize, DYN_LDS);

  hipLaunchKernelGGL(pack_w, dim3(96), dim3(256), 0, stream,
                     Wih_l, Whh_l, Wih_v, Whh_v, wp);
  hipLaunchKernelGGL(lvatt_main, dim3(NB / 128), dim3(512), DYN_LDS, stream,
                     obs, hid, W_le, b_le, W_ve, b_ve,
                     bih_l, bhh_l, bih_v, bhh_v,
                     W_lo, b_lo, W_vo, b_vo, W_at, b_at,
                     (const short8*)wp, (float*)d_out);
}